// Round 2
// baseline (290.040 us; speedup 1.0000x reference)
//
#include <hip/hip_runtime.h>

typedef __attribute__((ext_vector_type(4))) float f32x4;
typedef __attribute__((ext_vector_type(8))) short s16x8;
typedef __attribute__((ext_vector_type(4))) unsigned short u16x4;

struct F2 { float c, s; };

__device__ __forceinline__ unsigned short f2b(float f) {
  unsigned u = __builtin_bit_cast(unsigned, f);
  u += 0x7FFFu + ((u >> 16) & 1u);
  return (unsigned short)(u >> 16);
}
__device__ __forceinline__ void gll16(const void* g, void* l) {
  __builtin_amdgcn_global_load_lds(
      (const __attribute__((address_space(1))) unsigned int*)g,
      (__attribute__((address_space(3))) unsigned int*)l, 16, 0, 0);
}
__device__ __forceinline__ f32x4 mfma16(s16x8 a, s16x8 b, f32x4 c) {
  return __builtin_amdgcn_mfma_f32_16x16x32_bf16(a, b, c, 0, 0, 0);
}

// ---------------- kernel 0: f32 -> bf16 conversion (inputs) -----------------------------
__global__ void k_cvt(const float* __restrict__ src, unsigned short* __restrict__ dst, int n4) {
  int i = blockIdx.x * 256 + threadIdx.x;
  int stride = gridDim.x * 256;
  for (; i < n4; i += stride) {
    f32x4 v = ((const f32x4*)src)[i];
    u16x4 o;
    o.x = f2b(v.x); o.y = f2b(v.y); o.z = f2b(v.z); o.w = f2b(v.w);
    ((u16x4*)dst)[i] = o;
  }
}

// ---------------- kernel 1: RoPE sin/cos table (pos 0..4095, 16 pair-freqs) -------------
__global__ void k_sincos(F2* __restrict__ tab) {
  int idx = blockIdx.x * 256 + threadIdx.x;   // 65536 entries
  int pos = idx >> 4, fi = idx & 15;
  double inv = exp((double)fi * (-9.210340371976184 / 16.0));  // 10000^(-fi/16)
  double a = (double)pos * inv;
  F2 r; r.c = (float)cos(a); r.s = (float)sin(a);
  tab[idx] = r;
}

// ---------------- kernel 2: transpose weights f32 [K][N] -> bf16 [N][K] -----------------
__global__ void k_transpose(const float* __restrict__ wq,
                            const float* __restrict__ wk,
                            const float* __restrict__ wv,
                            const float* __restrict__ wo,
                            unsigned short* __restrict__ wtqkv,
                            unsigned short* __restrict__ wto) {
  __shared__ unsigned short tile[32][33];
  int z = blockIdx.z;
  const float* src = (z == 0) ? wq : (z == 1) ? wk : (z == 2) ? wv : wo;
  unsigned short* dst = (z < 3) ? (wtqkv + (size_t)z * 1048576) : wto;
  int bx = blockIdx.x * 32, by = blockIdx.y * 32;
  tile[threadIdx.y][threadIdx.x] = f2b(src[(size_t)(by + threadIdx.y) * 1024 + bx + threadIdx.x]);
  __syncthreads();
  dst[(size_t)(bx + threadIdx.y) * 1024 + by + threadIdx.x] = tile[threadIdx.x][threadIdx.y];
}

// ---------------- kernel 3: fused QKV projection GEMM + bias + RoPE + q-scale -----------
// X[16384][1024] @ WT[3072][1024]^T ; N-tiles 0-7 = q, 8-15 = k, 16-23 = v
// outputs laid out [bn*16+h][s][64] for the attention kernel.
__global__ __launch_bounds__(256, 2) void k_qkv(
    const unsigned short* __restrict__ Xq,
    const unsigned short* __restrict__ Xkv,
    const unsigned short* __restrict__ WT,
    const float* __restrict__ bq,
    const float* __restrict__ bk,
    const float* __restrict__ bv,
    const F2* __restrict__ tab,
    unsigned short* __restrict__ qbuf,
    unsigned short* __restrict__ kbuf,
    unsigned short* __restrict__ vbuf) {
  __shared__ __align__(16) unsigned short Al[128 * 64];
  __shared__ __align__(16) unsigned short Bl[128 * 64];
  int bid = blockIdx.x;                       // 3072
  int swz = (bid & 7) * 384 + (bid >> 3);     // XCD-aware, bijective (3072 % 8 == 0)
  int mt = swz / 24, nt = swz % 24;
  int m0 = mt * 128, n0 = nt * 128;
  int which = n0 >> 10;                       // 0=q 1=k 2=v (BN=128 divides 1024)
  const unsigned short* X = (which == 0) ? Xq : Xkv;
  const float* bias = (which == 0) ? bq : (which == 1) ? bk : bv;
  unsigned short* dst = (which == 0) ? qbuf : (which == 1) ? kbuf : vbuf;
  int n0l = n0 & 1023;
  int tid = threadIdx.x, wid = tid >> 6, lane = tid & 63;
  int fr = lane & 15, fg = lane >> 4;
  int wr = (wid >> 1) * 64, wc = (wid & 1) * 64;
  int sr = lane >> 3, sc8 = (lane & 7) * 8;

  f32x4 acc[4][4] = {};
  for (int kt = 0; kt < 16; ++kt) {
    int kb = kt * 64;
#pragma unroll
    for (int tt = 0; tt < 4; ++tt) {
      int t = wid * 4 + tt;
      gll16(X  + (size_t)(m0 + t * 8 + sr) * 1024 + kb + sc8, &Al[t * 512]);
      gll16(WT + (size_t)(n0 + t * 8 + sr) * 1024 + kb + sc8, &Bl[t * 512]);
    }
    __syncthreads();
#pragma unroll
    for (int ks = 0; ks < 2; ++ks) {
      int ko = ks * 32 + fg * 8;
      s16x8 af[4], bfr[4];
#pragma unroll
      for (int i = 0; i < 4; ++i) af[i]  = *(const s16x8*)&Al[(wr + i * 16 + fr) * 64 + ko];
#pragma unroll
      for (int i = 0; i < 4; ++i) bfr[i] = *(const s16x8*)&Bl[(wc + i * 16 + fr) * 64 + ko];
#pragma unroll
      for (int mi = 0; mi < 4; ++mi)
#pragma unroll
        for (int ni = 0; ni < 4; ++ni)
          acc[mi][ni] = mfma16(af[mi], bfr[ni], acc[mi][ni]);
    }
    __syncthreads();
  }
  // epilogue: C/D layout col = lane&15, row = (lane>>4)*4 + j  [verified m89]
#pragma unroll
  for (int mi = 0; mi < 4; ++mi)
#pragma unroll
    for (int ni = 0; ni < 4; ++ni) {
      int c = wc + ni * 16 + fr;
      int col = n0l + c;                       // 0..1023
      int h = col >> 6, d = col & 63;
      float bz = bias[col];
      bool rope = (which < 2) && (d < 32);     // wave-uniform per (ni)
#pragma unroll
      for (int j = 0; j < 4; ++j) {
        int mg = m0 + wr + mi * 16 + fg * 4 + j;
        float v = acc[mi][ni][j] + bz;
        if (rope) {
          float p = __shfl_xor(v, 1);          // partner col d^1 (lane bit0)
          F2 cs = tab[(mg & 4095) * 16 + (d >> 1)];
          v = (d & 1) ? fmaf(v, cs.c, p * cs.s) : fmaf(v, cs.c, -(p * cs.s));
        }
        if (which == 0) v *= 0.125f;           // 1/sqrt(D)
        int bn = mg >> 8, s2 = mg & 255;
        dst[((size_t)(bn * 16 + h) * 256 + s2) * 64 + d] = f2b(v);
      }
    }
}

// ---------------- kernel 4: attention per (bn, h) ---------------------------------------
__global__ __launch_bounds__(256, 1) void k_attn(
    const unsigned short* __restrict__ qbuf,
    const unsigned short* __restrict__ kbuf,
    const unsigned short* __restrict__ vbuf,
    unsigned short* __restrict__ xbuf) {
  __shared__ __align__(16) unsigned short Kl[256 * 64];      // 16B-chunk XOR-swizzled
  __shared__ __align__(16) unsigned short Vt[64 * 264];      // V^T, padded stride 264
  __shared__ __align__(16) unsigned short Pl[4][16 * 264];   // per-wave P tile
  int g = blockIdx.x;                 // 1024 = (bn<<4)|h
  size_t base = (size_t)g * (256 * 64);
  const unsigned short* Q = qbuf + base;
  const unsigned short* K = kbuf + base;
  const unsigned short* V = vbuf + base;
  int bn = g >> 4, h = g & 15;
  int tid = threadIdx.x, wid = tid >> 6, lane = tid & 63;
  int fr = lane & 15, fg = lane >> 4;

  // stage K: linear LDS dest, inverse-swizzled global source (rule #21)
#pragma unroll
  for (int tt = 0; tt < 8; ++tt) {
    int t = wid * 8 + tt;
    int r = t * 8 + (lane >> 3);
    int cp = lane & 7;
    int csrc = cp ^ (r & 7);
    gll16(K + r * 64 + csrc * 8, &Kl[t * 512]);
  }
  // stage V transposed: Vt[d][s]
#pragma unroll
  for (int c8 = 0; c8 < 8; ++c8) {
    s16x8 vv = *(const s16x8*)&V[tid * 64 + c8 * 8];
#pragma unroll
    for (int j = 0; j < 8; ++j)
      Vt[(c8 * 8 + j) * 264 + tid] = (unsigned short)vv[j];
  }
  __syncthreads();

  unsigned short* P = Pl[wid];
  int f7 = fr & 7;
  int c0 = (fg ^ f7) * 8;             // swizzled chunk, ks=0
  int c1 = ((4 + fg) ^ f7) * 8;       // ks=1
  for (int mtile = 0; mtile < 4; ++mtile) {
    int q0 = wid * 64 + mtile * 16;
    s16x8 qa0 = *(const s16x8*)&Q[(q0 + fr) * 64 + fg * 8];
    s16x8 qa1 = *(const s16x8*)&Q[(q0 + fr) * 64 + 32 + fg * 8];
    f32x4 sc[16] = {};
#pragma unroll
    for (int nt = 0; nt < 16; ++nt) {
      int rr = nt * 16 + fr;
      s16x8 kb0 = *(const s16x8*)&Kl[rr * 64 + c0];
      sc[nt] = mfma16(qa0, kb0, sc[nt]);
      s16x8 kb1 = *(const s16x8*)&Kl[rr * 64 + c1];
      sc[nt] = mfma16(qa1, kb1, sc[nt]);
    }
    // in-register softmax: row = fg*4 + j, cols spread over (nt, lane&15)
    float rs[4];
#pragma unroll
    for (int j = 0; j < 4; ++j) {
      float m = sc[0][j];
#pragma unroll
      for (int nt = 1; nt < 16; ++nt) m = fmaxf(m, sc[nt][j]);
      m = fmaxf(m, __shfl_xor(m, 1));
      m = fmaxf(m, __shfl_xor(m, 2));
      m = fmaxf(m, __shfl_xor(m, 4));
      m = fmaxf(m, __shfl_xor(m, 8));
      float sum = 0.f;
#pragma unroll
      for (int nt = 0; nt < 16; ++nt) {
        float p = __expf(sc[nt][j] - m);
        sum += p;
        P[(fg * 4 + j) * 264 + nt * 16 + fr] = f2b(p);
      }
      sum += __shfl_xor(sum, 1);
      sum += __shfl_xor(sum, 2);
      sum += __shfl_xor(sum, 4);
      sum += __shfl_xor(sum, 8);
      rs[j] = 1.0f / sum;             // deferred normalization
    }
    // PV: A = P (rows = lane&15, k contiguous), B = V^T rows (d = lane&15)
    f32x4 o[4] = {};
#pragma unroll
    for (int ks = 0; ks < 8; ++ks) {
      s16x8 pa = *(const s16x8*)&P[fr * 264 + ks * 32 + fg * 8];
#pragma unroll
      for (int nt = 0; nt < 4; ++nt) {
        s16x8 vb = *(const s16x8*)&Vt[(nt * 16 + fr) * 264 + ks * 32 + fg * 8];
        o[nt] = mfma16(pa, vb, o[nt]);
      }
    }
#pragma unroll
    for (int nt = 0; nt < 4; ++nt)
#pragma unroll
      for (int j = 0; j < 4; ++j) {
        int srow = q0 + fg * 4 + j;
        int d = nt * 16 + fr;
        xbuf[((size_t)(bn * 256 + srow)) * 1024 + h * 64 + d] = f2b(o[nt][j] * rs[j]);
      }
  }
}

// ---------------- kernel 5: output projection GEMM + bo (f32 output) --------------------
__global__ __launch_bounds__(256, 2) void k_out(
    const unsigned short* __restrict__ Xb,
    const unsigned short* __restrict__ WT,
    const float* __restrict__ bo,
    float* __restrict__ out) {
  __shared__ __align__(16) unsigned short Al[128 * 64];
  __shared__ __align__(16) unsigned short Bl[128 * 64];
  int bid = blockIdx.x;                        // 1024
  int swz = (bid & 7) * 128 + (bid >> 3);
  int mt = swz >> 3, nt = swz & 7;
  int m0 = mt * 128, n0 = nt * 128;
  int tid = threadIdx.x, wid = tid >> 6, lane = tid & 63;
  int fr = lane & 15, fg = lane >> 4;
  int wr = (wid >> 1) * 64, wc = (wid & 1) * 64;
  int sr = lane >> 3, sc8 = (lane & 7) * 8;
  f32x4 acc[4][4] = {};
  for (int kt = 0; kt < 16; ++kt) {
    int kb = kt * 64;
#pragma unroll
    for (int tt = 0; tt < 4; ++tt) {
      int t = wid * 4 + tt;
      gll16(Xb + (size_t)(m0 + t * 8 + sr) * 1024 + kb + sc8, &Al[t * 512]);
      gll16(WT + (size_t)(n0 + t * 8 + sr) * 1024 + kb + sc8, &Bl[t * 512]);
    }
    __syncthreads();
#pragma unroll
    for (int ks = 0; ks < 2; ++ks) {
      int ko = ks * 32 + fg * 8;
      s16x8 af[4], bfr[4];
#pragma unroll
      for (int i = 0; i < 4; ++i) af[i]  = *(const s16x8*)&Al[(wr + i * 16 + fr) * 64 + ko];
#pragma unroll
      for (int i = 0; i < 4; ++i) bfr[i] = *(const s16x8*)&Bl[(wc + i * 16 + fr) * 64 + ko];
#pragma unroll
      for (int mi = 0; mi < 4; ++mi)
#pragma unroll
        for (int ni = 0; ni < 4; ++ni)
          acc[mi][ni] = mfma16(af[mi], bfr[ni], acc[mi][ni]);
    }
    __syncthreads();
  }
#pragma unroll
  for (int mi = 0; mi < 4; ++mi)
#pragma unroll
    for (int ni = 0; ni < 4; ++ni) {
      int c = wc + ni * 16 + fr;
      float bz = bo[n0 + c];
#pragma unroll
      for (int j = 0; j < 4; ++j) {
        int mg = m0 + wr + mi * 16 + fg * 4 + j;
        out[(size_t)mg * 1024 + n0 + c] = acc[mi][ni][j] + bz;
      }
    }
}

extern "C" void kernel_launch(void* const* d_in, const int* in_sizes, int n_in,
                              void* d_out, int out_size, void* d_ws, size_t ws_size,
                              hipStream_t stream) {
  const float* Xq  = (const float*)d_in[0];
  const float* Xkv = (const float*)d_in[1];
  const float* Wq  = (const float*)d_in[2];
  const float* bq  = (const float*)d_in[3];
  const float* Wk  = (const float*)d_in[4];
  const float* bk  = (const float*)d_in[5];
  const float* Wv  = (const float*)d_in[6];
  const float* bv  = (const float*)d_in[7];
  const float* Wo  = (const float*)d_in[8];
  const float* bo  = (const float*)d_in[9];
  float* out = (float*)d_out;

  char* ws = (char*)d_ws;
  size_t off = 0;
  F2* tab = (F2*)(ws + off);                           off += (size_t)65536 * sizeof(F2);   // 0.5 MB
  unsigned short* WTqkv = (unsigned short*)(ws + off); off += (size_t)3 * 1048576 * 2;      // 6 MB
  unsigned short* WTo   = (unsigned short*)(ws + off); off += (size_t)1048576 * 2;          // 2 MB
  unsigned short* Xqb   = (unsigned short*)(ws + off); off += (size_t)16777216 * 2;         // 32 MB
  unsigned short* Xkvb  = (unsigned short*)(ws + off); off += (size_t)16777216 * 2;         // 32 MB
  unsigned short* qb = (unsigned short*)(ws + off); off += (size_t)16777216 * 2;            // 32 MB
  unsigned short* kb = (unsigned short*)(ws + off); off += (size_t)16777216 * 2;
  unsigned short* vb = (unsigned short*)(ws + off); off += (size_t)16777216 * 2;
  unsigned short* xb = Xqb;   // alias: Xq_bf16 is dead after k_qkv, reused for attn output

  k_cvt<<<2048, 256, 0, stream>>>(Xq,  Xqb,  4194304);
  k_cvt<<<2048, 256, 0, stream>>>(Xkv, Xkvb, 4194304);
  k_sincos<<<256, 256, 0, stream>>>(tab);
  k_transpose<<<dim3(32, 32, 4), dim3(32, 32), 0, stream>>>(Wq, Wk, Wv, Wo, WTqkv, WTo);
  k_qkv<<<3072, 256, 0, stream>>>(Xqb, Xkvb, WTqkv, bq, bk, bv, tab, qb, kb, vb);
  k_attn<<<1024, 256, 0, stream>>>(qb, kb, vb, xb);
  k_out<<<1024, 256, 0, stream>>>(xb, WTo, bo, out);
}